// Round 2
// baseline (259.117 us; speedup 1.0000x reference)
//
#include <hip/hip_runtime.h>

#define BB 4
#define HH 8
#define SS 2048
#define DD 32
#define DMODEL 256
#define NEG_BIG_F (-1000000000.0f)
#define SCALE 0.17677669529663687f

typedef short short8 __attribute__((ext_vector_type(8)));
typedef float float4_ __attribute__((ext_vector_type(4)));

__device__ __forceinline__ unsigned short f2bf(float x) {
  unsigned u = __float_as_uint(x);
  u += 0x7FFFu + ((u >> 16) & 1u);
  return (unsigned short)(u >> 16);
}

// ---------------- Kernel 1: fused Q/K/V projections -> bf16, head-split ----
// qh/kh/vh layout: [b][h][s][d], d contiguous (32 bf16 = 64B rows)
__global__ __launch_bounds__(256) void proj_kernel(
    const float* __restrict__ q, const float* __restrict__ k,
    const float* __restrict__ v,
    const float* __restrict__ Wq, const float* __restrict__ Wk,
    const float* __restrict__ Wv,
    unsigned short* __restrict__ qh, unsigned short* __restrict__ kh,
    unsigned short* __restrict__ vh) {
  int z = blockIdx.z;
  const float* src = (z == 0) ? q : (z == 1) ? k : v;
  const float* W = (z == 0) ? Wq : (z == 1) ? Wk : Wv;
  unsigned short* dst = (z == 0) ? qh : (z == 1) ? kh : vh;

  int w = threadIdx.x >> 6;
  int lane = threadIdx.x & 63;
  int l16 = lane & 15;
  int g = lane >> 4;

  int row = blockIdx.x * 64 + w * 16 + l16;  // A-frag row
  int n0 = blockIdx.y * 64;

  float4_ z4 = {0.f, 0.f, 0.f, 0.f};
  float4_ acc[4] = {z4, z4, z4, z4};

  for (int k0 = 0; k0 < DMODEL; k0 += 32) {
    const float* ap = src + (size_t)row * DMODEL + k0 + 8 * g;
    short8 a;
#pragma unroll
    for (int j = 0; j < 8; ++j) a[j] = (short)f2bf(ap[j]);
#pragma unroll
    for (int cb = 0; cb < 4; ++cb) {
      int n = n0 + cb * 16 + l16;
      short8 bfr;
#pragma unroll
      for (int j = 0; j < 8; ++j)
        bfr[j] = (short)f2bf(W[(size_t)(k0 + 8 * g + j) * DMODEL + n]);
      acc[cb] = __builtin_amdgcn_mfma_f32_16x16x32_bf16(a, bfr, acc[cb], 0, 0, 0);
    }
  }

  int rowbase = blockIdx.x * 64 + w * 16 + 4 * g;
#pragma unroll
  for (int cb = 0; cb < 4; ++cb) {
#pragma unroll
    for (int rr = 0; rr < 4; ++rr) {
      int r = rowbase + rr;
      int c = n0 + cb * 16 + l16;
      int b = r >> 11, s = r & (SS - 1);
      int h = c >> 5, d = c & 31;
      dst[(((size_t)(b * HH + h) * SS + s) * DD) + d] = f2bf(acc[cb][rr]);
    }
  }
}

// ---------------- Kernel 2: softmax stats (m, l) per row, online -----------
__global__ __launch_bounds__(256) void stats_kernel(
    const unsigned short* __restrict__ qh, const unsigned short* __restrict__ kh,
    const float* __restrict__ mask, float* __restrict__ m_arr,
    float* __restrict__ l_arr) {
  __shared__ float bias[SS];
  int bh = blockIdx.y;
  int b = bh >> 3;
  for (int i = threadIdx.x; i < SS; i += 256)
    bias[i] = (1.0f - mask[(size_t)b * SS + i]) * NEG_BIG_F;
  __syncthreads();

  int w = threadIdx.x >> 6, lane = threadIdx.x & 63, l16 = lane & 15,
      g = lane >> 4;
  int q0 = blockIdx.x * 64 + w * 16;

  short8 qa = *(const short8*)(qh + ((size_t)bh * SS + q0 + l16) * DD + 8 * g);

  float m[4], l[4];
#pragma unroll
  for (int i = 0; i < 4; ++i) {
    m[i] = -INFINITY;
    l[i] = 0.f;
  }

  const unsigned short* kbase = kh + (size_t)bh * SS * DD;
  float4_ z4 = {0.f, 0.f, 0.f, 0.f};
  for (int k0 = 0; k0 < SS; k0 += 16) {
    short8 kf = *(const short8*)(kbase + (size_t)(k0 + l16) * DD + 8 * g);
    float4_ r = __builtin_amdgcn_mfma_f32_16x16x32_bf16(qa, kf, z4, 0, 0, 0);
    float bk = bias[k0 + l16];
#pragma unroll
    for (int rr = 0; rr < 4; ++rr) {
      float t = fmaf(r[rr], SCALE, bk);
      float nm = fmaxf(m[rr], t);
      l[rr] = l[rr] * __expf(m[rr] - nm) + __expf(t - nm);
      m[rr] = nm;
    }
  }
  // merge (m,l) across the 16 k-lanes of each g-group
#pragma unroll
  for (int off = 1; off < 16; off <<= 1) {
#pragma unroll
    for (int rr = 0; rr < 4; ++rr) {
      float om = __shfl_xor(m[rr], off);
      float ol = __shfl_xor(l[rr], off);
      float nm = fmaxf(m[rr], om);
      l[rr] = l[rr] * __expf(m[rr] - nm) + ol * __expf(om - nm);
      m[rr] = nm;
    }
  }
  if (l16 == 0) {
#pragma unroll
    for (int rr = 0; rr < 4; ++rr) {
      size_t idx = (size_t)bh * SS + q0 + 4 * g + rr;
      m_arr[idx] = m[rr];
      l_arr[idx] = l[rr];
    }
  }
}

// ---------------- Kernel 3: emit attn (fp32, write-once) + PV ctx ---------
__global__ __launch_bounds__(256) void emit_kernel(
    const unsigned short* __restrict__ qh, const unsigned short* __restrict__ kh,
    const unsigned short* __restrict__ vh, const float* __restrict__ mask,
    const float* __restrict__ m_arr, const float* __restrict__ l_arr,
    float* __restrict__ attn_out, unsigned short* __restrict__ concat) {
  __shared__ float bias[SS];
  __shared__ unsigned short vt[32][72];     // V^T tile, +8 pad -> 2-way banks
  __shared__ unsigned short at[4][16][72];  // per-wave P tile [16 q][64 k]+pad

  int bh = blockIdx.y;
  int b = bh >> 3, h = bh & 7;
  for (int i = threadIdx.x; i < SS; i += 256)
    bias[i] = (1.0f - mask[(size_t)b * SS + i]) * NEG_BIG_F;

  int w = threadIdx.x >> 6, lane = threadIdx.x & 63, l16 = lane & 15,
      g = lane >> 4;
  int q0 = blockIdx.x * 64 + w * 16;

  short8 qa = *(const short8*)(qh + ((size_t)bh * SS + q0 + l16) * DD + 8 * g);

  float mr[4], rl[4];
#pragma unroll
  for (int rr = 0; rr < 4; ++rr) {
    size_t idx = (size_t)bh * SS + q0 + 4 * g + rr;
    mr[rr] = m_arr[idx];
    rl[rr] = 1.0f / l_arr[idx];
  }

  const unsigned short* kbase = kh + (size_t)bh * SS * DD;
  const unsigned short* vbase = vh + (size_t)bh * SS * DD;
  float* arow = attn_out + (size_t)bh * SS * SS;

  float4_ z4 = {0.f, 0.f, 0.f, 0.f};
  float4_ acc0 = z4, acc1 = z4;

  int vr = threadIdx.x >> 2;         // 0..63: v-row in tile
  int dseg = (threadIdx.x & 3) * 8;  // d start

  for (int kb = 0; kb < SS; kb += 64) {
    __syncthreads();
    {  // stage V^T
      short8 vv = *(const short8*)(vbase + (size_t)(kb + vr) * DD + dseg);
#pragma unroll
      for (int j = 0; j < 8; ++j) vt[dseg + j][vr] = (unsigned short)vv[j];
    }
    __syncthreads();

#pragma unroll
    for (int ks = 0; ks < 2; ++ks) {
#pragma unroll
      for (int kt = 0; kt < 2; ++kt) {
        int k0 = kb + ks * 32 + kt * 16;
        short8 kf = *(const short8*)(kbase + (size_t)(k0 + l16) * DD + 8 * g);
        float4_ r = __builtin_amdgcn_mfma_f32_16x16x32_bf16(qa, kf, z4, 0, 0, 0);
        float bk = bias[k0 + l16];
#pragma unroll
        for (int rr = 0; rr < 4; ++rr) {
          float t = fmaf(r[rr], SCALE, bk);
          float p = __expf(t - mr[rr]) * rl[rr];
          arow[(size_t)(q0 + 4 * g + rr) * SS + k0 + l16] = p;
          at[w][4 * g + rr][ks * 32 + kt * 16 + l16] = f2bf(p);
        }
      }
      short8 pa = *(const short8*)&at[w][l16][ks * 32 + 8 * g];
      short8 b0 = *(const short8*)&vt[l16][ks * 32 + 8 * g];
      short8 b1 = *(const short8*)&vt[16 + l16][ks * 32 + 8 * g];
      acc0 = __builtin_amdgcn_mfma_f32_16x16x32_bf16(pa, b0, acc0, 0, 0, 0);
      acc1 = __builtin_amdgcn_mfma_f32_16x16x32_bf16(pa, b1, acc1, 0, 0, 0);
    }
  }

#pragma unroll
  for (int rr = 0; rr < 4; ++rr) {
    int s = q0 + 4 * g + rr;
    size_t base = ((size_t)b * SS + s) * DMODEL + h * DD;
    concat[base + l16] = f2bf(acc0[rr]);
    concat[base + 16 + l16] = f2bf(acc1[rr]);
  }
}

// ---------------- Kernel 4: out = concat @ Wo (fp32 out) ------------------
__global__ __launch_bounds__(256) void outgemm_kernel(
    const unsigned short* __restrict__ concat, const float* __restrict__ Wo,
    float* __restrict__ out) {
  int w = threadIdx.x >> 6, lane = threadIdx.x & 63, l16 = lane & 15,
      g = lane >> 4;
  int row = blockIdx.x * 64 + w * 16 + l16;
  int n0 = blockIdx.y * 64;
  float4_ z4 = {0.f, 0.f, 0.f, 0.f};
  float4_ acc[4] = {z4, z4, z4, z4};
  for (int k0 = 0; k0 < DMODEL; k0 += 32) {
    short8 a = *(const short8*)(concat + (size_t)row * DMODEL + k0 + 8 * g);
#pragma unroll
    for (int cb = 0; cb < 4; ++cb) {
      int n = n0 + cb * 16 + l16;
      short8 bfr;
#pragma unroll
      for (int j = 0; j < 8; ++j)
        bfr[j] = (short)f2bf(Wo[(size_t)(k0 + 8 * g + j) * DMODEL + n]);
      acc[cb] = __builtin_amdgcn_mfma_f32_16x16x32_bf16(a, bfr, acc[cb], 0, 0, 0);
    }
  }
  int rowbase = blockIdx.x * 64 + w * 16 + 4 * g;
#pragma unroll
  for (int cb = 0; cb < 4; ++cb)
#pragma unroll
    for (int rr = 0; rr < 4; ++rr)
      out[(size_t)(rowbase + rr) * DMODEL + n0 + cb * 16 + l16] = acc[cb][rr];
}

extern "C" void kernel_launch(void* const* d_in, const int* in_sizes, int n_in,
                              void* d_out, int out_size, void* d_ws,
                              size_t ws_size, hipStream_t stream) {
  const float* v = (const float*)d_in[0];
  const float* k = (const float*)d_in[1];
  const float* q = (const float*)d_in[2];
  const float* mask = (const float*)d_in[3];
  const float* Wq = (const float*)d_in[4];
  const float* Wk = (const float*)d_in[5];
  const float* Wv = (const float*)d_in[6];
  const float* Wo = (const float*)d_in[7];

  float* out = (float*)d_out;                          // [B,S,256]
  float* attn = out + (size_t)BB * SS * DMODEL;        // [B,H,S,S]

  const size_t NH = (size_t)BB * HH * SS * DD;  // 2,097,152
  unsigned short* qh = (unsigned short*)d_ws;
  unsigned short* kh = qh + NH;
  unsigned short* vh = kh + NH;
  unsigned short* concat = vh + NH;  // [B,S,256] bf16
  float* m_arr = (float*)(concat + (size_t)BB * SS * DMODEL);
  float* l_arr = m_arr + (size_t)BB * HH * SS;

  proj_kernel<<<dim3(128, 4, 3), 256, 0, stream>>>(q, k, v, Wq, Wk, Wv, qh, kh,
                                                   vh);
  stats_kernel<<<dim3(32, 32), 256, 0, stream>>>(qh, kh, mask, m_arr, l_arr);
  emit_kernel<<<dim3(32, 32), 256, 0, stream>>>(qh, kh, vh, mask, m_arr, l_arr,
                                                attn, concat);
  outgemm_kernel<<<dim3(128, 4), 256, 0, stream>>>(concat, Wo, out);
}